// Round 1
// baseline (693.224 us; speedup 1.0000x reference)
//
#include <hip/hip_runtime.h>
#include <hip/hip_bf16.h>
#include <math.h>

#define TOK  8192
#define NE   64
#define NH   5120
#define TOPK 8

// Kernel 1: partial logits. lane = token (64 tokens per wave), each lane
// accumulates all 64 expert dots over its H-slice. Weights are wave-uniform
// -> scalar loads; x is per-lane streamed global_load_dwordx4.
__global__ __launch_bounds__(256) void gate_partial_k(
    const float* __restrict__ x, const float* __restrict__ w,
    float* __restrict__ ws, int HS)
{
    const int lane = threadIdx.x & 63;
    // readfirstlane so the compiler PROVES wave-uniformity of weight addresses
    const int wid  = __builtin_amdgcn_readfirstlane((int)(threadIdx.x >> 6));
    const int tg   = blockIdx.x;            // token group 0..127
    const int hs   = blockIdx.y * 4 + wid;  // h-slice 0..HS-1
    const int HLEN = NH / HS;
    const int h0   = hs * HLEN;
    const int t    = tg * 64 + lane;

    const float* __restrict__ xrow  = x + (size_t)t * NH + h0;
    const float* __restrict__ wbase = w + h0;

    float acc[NE];
#pragma unroll
    for (int e = 0; e < NE; ++e) acc[e] = 0.f;

    for (int h = 0; h < HLEN; h += 4) {
        const float4 xv = *reinterpret_cast<const float4*>(xrow + h);
#pragma unroll
        for (int e = 0; e < NE; ++e) {
            const float* wp = wbase + (size_t)e * NH + h;  // uniform -> s_load
            acc[e] = fmaf(xv.x, wp[0],
                     fmaf(xv.y, wp[1],
                     fmaf(xv.z, wp[2],
                     fmaf(xv.w, wp[3], acc[e]))));
        }
    }

    // ws[hs][tg][e][lane]  (coalesced stores across lanes)
    float* outp = ws + (((size_t)hs * 128 + tg) * NE) * 64 + lane;
#pragma unroll
    for (int e = 0; e < NE; ++e) outp[(size_t)e * 64] = acc[e];
}

// Kernel 2: reduce partials, add bias, lane-local top-8 + softmax, write out.
__global__ __launch_bounds__(256) void gate_topk_k(
    const float* __restrict__ ws, const float* __restrict__ bias,
    float* __restrict__ out, int HS)
{
    const int lane = threadIdx.x & 63;
    const int wid  = __builtin_amdgcn_readfirstlane((int)(threadIdx.x >> 6));
    const int tg   = blockIdx.x * 4 + wid;  // 0..127
    const int t    = tg * 64 + lane;

    float acc[NE];
#pragma unroll
    for (int e = 0; e < NE; ++e) acc[e] = bias[e];   // uniform -> s_load

    for (int hs = 0; hs < HS; ++hs) {
        const float* p = ws + (((size_t)hs * 128 + tg) * NE) * 64 + lane;
#pragma unroll
        for (int e = 0; e < NE; ++e) acc[e] += p[(size_t)e * 64];
    }

    // top-8, strict > keeps lowest index on ties (matches lax.top_k)
    float vals[TOPK]; int idxs[TOPK];
#pragma unroll
    for (int k = 0; k < TOPK; ++k) {
        float m = -INFINITY; int mi = 0;
#pragma unroll
        for (int e = 0; e < NE; ++e) {
            const bool b = acc[e] > m;
            m  = b ? acc[e] : m;
            mi = b ? e  : mi;
        }
        vals[k] = m; idxs[k] = mi;
#pragma unroll
        for (int e = 0; e < NE; ++e)        // static index, runtime compare
            acc[e] = (e == mi) ? -INFINITY : acc[e];
    }

    // softmax over the 8 (vals[0] is the max)
    float wts[TOPK];
    float s = 0.f;
#pragma unroll
    for (int k = 0; k < TOPK; ++k) { wts[k] = __expf(vals[k] - vals[0]); s += wts[k]; }
    const float inv = 1.f / s;
#pragma unroll
    for (int k = 0; k < TOPK; ++k) wts[k] *= inv;

    float4 i0, i1, w0, w1;
    i0.x = (float)idxs[0]; i0.y = (float)idxs[1]; i0.z = (float)idxs[2]; i0.w = (float)idxs[3];
    i1.x = (float)idxs[4]; i1.y = (float)idxs[5]; i1.z = (float)idxs[6]; i1.w = (float)idxs[7];
    w0.x = wts[0]; w0.y = wts[1]; w0.z = wts[2]; w0.w = wts[3];
    w1.x = wts[4]; w1.y = wts[5]; w1.z = wts[6]; w1.w = wts[7];

    float* oi = out + (size_t)t * TOPK;                     // indices (as float)
    float* ow = out + (size_t)TOK * TOPK + (size_t)t * TOPK; // weights
    *reinterpret_cast<float4*>(oi)     = i0;
    *reinterpret_cast<float4*>(oi + 4) = i1;
    *reinterpret_cast<float4*>(ow)     = w0;
    *reinterpret_cast<float4*>(ow + 4) = w1;
}

extern "C" void kernel_launch(void* const* d_in, const int* in_sizes, int n_in,
                              void* d_out, int out_size, void* d_ws, size_t ws_size,
                              hipStream_t stream)
{
    const float* x    = (const float*)d_in[0];
    const float* w    = (const float*)d_in[1];
    const float* bias = (const float*)d_in[2];
    float* out = (float*)d_out;
    float* ws  = (float*)d_ws;

    // partial buffer: HS * 128 * 64 * 64 floats; prefer HS=16 (2 waves/SIMD)
    int HS = 16;
    while (HS > 4 && (size_t)HS * 128 * NE * 64 * sizeof(float) > ws_size) HS >>= 1;

    dim3 g1(128, HS / 4);
    gate_partial_k<<<g1, 256, 0, stream>>>(x, w, ws, HS);
    gate_topk_k<<<dim3(32), 256, 0, stream>>>(ws, bias, out, HS);
}

// Round 5
// 371.321 us; speedup vs baseline: 1.8669x; 1.8669x over previous
//
#include <hip/hip_runtime.h>
#include <hip/hip_bf16.h>
#include <math.h>

#define TOK  8192
#define NE   64
#define NH   5120
#define TOPK 8
#define KS   8              // K-split for occupancy + accumulation-error control
#define KLEN (NH / KS)      // 640
#define NTG  (TOK / 64)     // 128 token groups of 64
#define NP   (NE * NH / 2)  // u32 words per packed bf16 plane

typedef __attribute__((ext_vector_type(8))) short bf16x8;   // 8 bf16 (4 VGPRs)
typedef __attribute__((ext_vector_type(4))) float f32x4;

union Frag { unsigned int u[4]; bf16x8 v; };

// 3-way truncation split: x = hi + mid + lo, each bf16 (8 mantissa bits).
// hi/mid exact truncations, lo rounded half-up. Packs element pair (x0,x1)
// into one u32 per plane via v_perm — IDENTICAL packing for A and B, so any
// within-pair k-permutation cancels in the MFMA dot product.
__device__ __forceinline__ void split3_2(float x0, float x1,
    unsigned int& hi, unsigned int& mid, unsigned int& lo)
{
    unsigned int u0 = __float_as_uint(x0), u1 = __float_as_uint(x1);
    float h0 = __uint_as_float(u0 & 0xffff0000u);    // exact bf16 trunc
    float h1 = __uint_as_float(u1 & 0xffff0000u);
    hi = __builtin_amdgcn_perm(u1, u0, 0x07060302u);
    float r0 = x0 - h0, r1 = x1 - h1;                // exact residual
    unsigned int m0u = __float_as_uint(r0) & 0xffff0000u;
    unsigned int m1u = __float_as_uint(r1) & 0xffff0000u;
    mid = __builtin_amdgcn_perm(m1u, m0u, 0x07060302u);
    float l0 = r0 - __uint_as_float(m0u);            // exact residual
    float l1 = r1 - __uint_as_float(m1u);
    unsigned int v0 = __float_as_uint(l0) + 0x8000u; // round-half-up to bf16
    unsigned int v1 = __float_as_uint(l1) + 0x8000u;
    lo = __builtin_amdgcn_perm(v1, v0, 0x07060302u);
}

// Kernel 0: weights fp32 [64][5120] -> 3 packed bf16 planes (hi, mid, lo).
__global__ __launch_bounds__(256) void wsplit_k(const float* __restrict__ w,
                                                unsigned int* __restrict__ whl)
{
    const int t = blockIdx.x * 256 + threadIdx.x;   // 81920 threads, 4 elems each
    const float4 v = *reinterpret_cast<const float4*>(w + (size_t)t * 4);
    unsigned int h0, m0, l0, h1, m1, l1;
    split3_2(v.x, v.y, h0, m0, l0);
    split3_2(v.z, v.w, h1, m1, l1);
    whl[2 * t]              = h0;  whl[2 * t + 1]              = h1;  // hi
    whl[NP + 2 * t]         = m0;  whl[NP + 2 * t + 1]         = m1;  // mid
    whl[2 * NP + 2 * t]     = l0;  whl[2 * NP + 2 * t + 1]     = l1;  // lo
}

// Kernel 1: triple-split bf16 MFMA GEMM. Block = 64 tokens x 64 experts x KLEN.
// Wave w owns 16 tokens; A fp32 loaded per-lane from HBM, split in-register;
// B planes per-lane (L1/L2-resident). No LDS, no barriers.
__global__ __launch_bounds__(256, 4) void gemm_k(
    const float* __restrict__ x, const unsigned int* __restrict__ whl,
    float* __restrict__ part)
{
    const int lane = threadIdx.x & 63;
    const int wv   = threadIdx.x >> 6;       // 0..3
    const int tg   = blockIdx.x;             // 0..127
    const int ks   = blockIdx.y;             // 0..7
    const int arow = lane & 15;              // A row (token) / B col (expert)
    const int kg   = lane >> 4;              // k-group: elems kg*8..kg*8+7

    const float* xrow = x + (size_t)(tg * 64 + wv * 16 + arow) * NH
                          + ks * KLEN + kg * 8;
    const unsigned int* wh = whl + ks * (KLEN / 2) + kg * 4;

    f32x4 acc[4];
#pragma unroll
    for (int n = 0; n < 4; ++n) acc[n] = (f32x4){0.f, 0.f, 0.f, 0.f};

    for (int kk = 0; kk < KLEN / 32; ++kk) {          // 20 steps
        const float4 a0 = *reinterpret_cast<const float4*>(xrow + kk * 32);
        const float4 a1 = *reinterpret_cast<const float4*>(xrow + kk * 32 + 4);
        Frag ah, am, al;
        split3_2(a0.x, a0.y, ah.u[0], am.u[0], al.u[0]);
        split3_2(a0.z, a0.w, ah.u[1], am.u[1], al.u[1]);
        split3_2(a1.x, a1.y, ah.u[2], am.u[2], al.u[2]);
        split3_2(a1.z, a1.w, ah.u[3], am.u[3], al.u[3]);
#pragma unroll
        for (int n = 0; n < 4; ++n) {
            const size_t erow = (size_t)(n * 16 + arow) * (NH / 2) + kk * 16;
            Frag bh, bm, bl;
            *reinterpret_cast<int4*>(bh.u) =
                *reinterpret_cast<const int4*>(wh + erow);
            *reinterpret_cast<int4*>(bm.u) =
                *reinterpret_cast<const int4*>(wh + NP + erow);
            *reinterpret_cast<int4*>(bl.u) =
                *reinterpret_cast<const int4*>(wh + 2 * NP + erow);
            acc[n] = __builtin_amdgcn_mfma_f32_16x16x32_bf16(ah.v, bh.v, acc[n], 0, 0, 0);
            acc[n] = __builtin_amdgcn_mfma_f32_16x16x32_bf16(am.v, bh.v, acc[n], 0, 0, 0);
            acc[n] = __builtin_amdgcn_mfma_f32_16x16x32_bf16(ah.v, bm.v, acc[n], 0, 0, 0);
            acc[n] = __builtin_amdgcn_mfma_f32_16x16x32_bf16(am.v, bm.v, acc[n], 0, 0, 0);
            acc[n] = __builtin_amdgcn_mfma_f32_16x16x32_bf16(al.v, bh.v, acc[n], 0, 0, 0);
            acc[n] = __builtin_amdgcn_mfma_f32_16x16x32_bf16(ah.v, bl.v, acc[n], 0, 0, 0);
        }
    }

    // C layout (16x16x32): col(expert)=lane&15, row(token)=(lane>>4)*4+i.
    float* pb = part + (((size_t)ks * NTG + tg) * 64) * 64;
#pragma unroll
    for (int n = 0; n < 4; ++n)
#pragma unroll
        for (int i = 0; i < 4; ++i) {
            const int tokl = wv * 16 + kg * 4 + i;
            const int e    = n * 16 + arow;
            pb[(size_t)tokl * 64 + e] = acc[n][i];
        }
}

// Kernel 2: reduce K-split partials + bias, lane-local top-8 + softmax.
__global__ __launch_bounds__(256) void gate_topk_k(
    const float* __restrict__ part, const float* __restrict__ bias,
    float* __restrict__ out)
{
    const int lane = threadIdx.x & 63;
    const int wid  = __builtin_amdgcn_readfirstlane((int)(threadIdx.x >> 6));
    const int tg   = blockIdx.x * 4 + wid;   // 0..127
    const int t    = tg * 64 + lane;

    float acc[NE];
#pragma unroll
    for (int e = 0; e < NE; ++e) acc[e] = bias[e];   // uniform -> s_load

    for (int ks = 0; ks < KS; ++ks) {
        const float4* p = reinterpret_cast<const float4*>(
            part + (((size_t)ks * NTG + tg) * 64 + lane) * 64);
#pragma unroll
        for (int e4 = 0; e4 < 16; ++e4) {
            const float4 v = p[e4];
            acc[e4 * 4 + 0] += v.x; acc[e4 * 4 + 1] += v.y;
            acc[e4 * 4 + 2] += v.z; acc[e4 * 4 + 3] += v.w;
        }
    }

    // top-8, strict > keeps lowest index on ties (matches lax.top_k)
    float vals[TOPK]; int idxs[TOPK];
#pragma unroll
    for (int k = 0; k < TOPK; ++k) {
        float m = -INFINITY; int mi = 0;
#pragma unroll
        for (int e = 0; e < NE; ++e) {
            const bool b = acc[e] > m;
            m  = b ? acc[e] : m;
            mi = b ? e  : mi;
        }
        vals[k] = m; idxs[k] = mi;
#pragma unroll
        for (int e = 0; e < NE; ++e)
            acc[e] = (e == mi) ? -INFINITY : acc[e];
    }

    float wts[TOPK];
    float s = 0.f;
#pragma unroll
    for (int k = 0; k < TOPK; ++k) { wts[k] = __expf(vals[k] - vals[0]); s += wts[k]; }
    const float inv = 1.f / s;
#pragma unroll
    for (int k = 0; k < TOPK; ++k) wts[k] *= inv;

    float4 i0, i1, w0, w1;
    i0.x = (float)idxs[0]; i0.y = (float)idxs[1]; i0.z = (float)idxs[2]; i0.w = (float)idxs[3];
    i1.x = (float)idxs[4]; i1.y = (float)idxs[5]; i1.z = (float)idxs[6]; i1.w = (float)idxs[7];
    w0.x = wts[0]; w0.y = wts[1]; w0.z = wts[2]; w0.w = wts[3];
    w1.x = wts[4]; w1.y = wts[5]; w1.z = wts[6]; w1.w = wts[7];

    float* oi = out + (size_t)t * TOPK;
    float* ow = out + (size_t)TOK * TOPK + (size_t)t * TOPK;
    *reinterpret_cast<float4*>(oi)     = i0;
    *reinterpret_cast<float4*>(oi + 4) = i1;
    *reinterpret_cast<float4*>(ow)     = w0;
    *reinterpret_cast<float4*>(ow + 4) = w1;
}

extern "C" void kernel_launch(void* const* d_in, const int* in_sizes, int n_in,
                              void* d_out, int out_size, void* d_ws, size_t ws_size,
                              hipStream_t stream)
{
    const float* x    = (const float*)d_in[0];
    const float* w    = (const float*)d_in[1];
    const float* bias = (const float*)d_in[2];
    float* out = (float*)d_out;

    // ws layout: partials [KS][NTG][64 tok][64 e] f32 = 16.78 MB,
    // then 3 packed bf16 weight planes (hi/mid/lo) = 1.97 MB.
    float*        part = (float*)d_ws;
    unsigned int* whl  = (unsigned int*)((char*)d_ws
                         + (size_t)KS * NTG * 64 * 64 * sizeof(float));

    wsplit_k<<<dim3((NE * NH / 4) / 256), 256, 0, stream>>>(w, whl);
    gemm_k  <<<dim3(NTG, KS), 256, 0, stream>>>(x, whl, part);
    gate_topk_k<<<dim3(NTG / 4), 256, 0, stream>>>(part, bias, out);
}

// Round 7
// 358.966 us; speedup vs baseline: 1.9312x; 1.0344x over previous
//
#include <hip/hip_runtime.h>
#include <hip/hip_bf16.h>
#include <math.h>

#define TOK  8192
#define NE   64
#define NH   5120
#define TOPK 8
#define NTG  (TOK / 64)     // 128 token groups of 64
#define NP   (NE * NH / 2)  // u32 words per packed bf16 plane
#define LOGN (TOK * NE)     // logits element count (524288)

typedef __attribute__((ext_vector_type(8))) short bf16x8;   // 8 bf16 (4 VGPRs)
typedef __attribute__((ext_vector_type(4))) float f32x4;

union Frag { unsigned int u[4]; bf16x8 v; };

// 3-way truncation split: x = hi + mid + lo, each bf16 (8 mantissa bits).
// hi/mid exact truncations, lo rounded half-up. Packs element pair (x0,x1)
// into one u32 per plane via v_perm — IDENTICAL packing for A and B, so any
// within-pair k-permutation cancels in the MFMA dot product.
__device__ __forceinline__ void split3_2(float x0, float x1,
    unsigned int& hi, unsigned int& mid, unsigned int& lo)
{
    unsigned int u0 = __float_as_uint(x0), u1 = __float_as_uint(x1);
    float h0 = __uint_as_float(u0 & 0xffff0000u);    // exact bf16 trunc
    float h1 = __uint_as_float(u1 & 0xffff0000u);
    hi = __builtin_amdgcn_perm(u1, u0, 0x07060302u);
    float r0 = x0 - h0, r1 = x1 - h1;                // exact residual
    unsigned int m0u = __float_as_uint(r0) & 0xffff0000u;
    unsigned int m1u = __float_as_uint(r1) & 0xffff0000u;
    mid = __builtin_amdgcn_perm(m1u, m0u, 0x07060302u);
    float l0 = r0 - __uint_as_float(m0u);            // exact residual
    float l1 = r1 - __uint_as_float(m1u);
    unsigned int v0 = __float_as_uint(l0) + 0x8000u; // round-half-up to bf16
    unsigned int v1 = __float_as_uint(l1) + 0x8000u;
    lo = __builtin_amdgcn_perm(v1, v0, 0x07060302u);
}

// Kernel 0: weights fp32 [64][5120] -> 3 packed bf16 planes (hi, mid, lo).
__global__ __launch_bounds__(256) void wsplit_k(const float* __restrict__ w,
                                                unsigned int* __restrict__ whl)
{
    const int t = blockIdx.x * 256 + threadIdx.x;   // 81920 threads, 4 elems each
    const float4 v = *reinterpret_cast<const float4*>(w + (size_t)t * 4);
    unsigned int h0, m0, l0, h1, m1, l1;
    split3_2(v.x, v.y, h0, m0, l0);
    split3_2(v.z, v.w, h1, m1, l1);
    whl[2 * t]              = h0;  whl[2 * t + 1]              = h1;  // hi
    whl[NP + 2 * t]         = m0;  whl[NP + 2 * t + 1]         = m1;  // mid
    whl[2 * NP + 2 * t]     = l0;  whl[2 * NP + 2 * t + 1]     = l1;  // lo
}

// Kernel 1: triple-split bf16 MFMA GEMM. Block = 64 tokens x 64 experts x KLEN.
// Wave w owns 16 tokens; A fp32 loaded per-lane from HBM, split in-register;
// B planes per-lane (L2-resident). No LDS, no barriers.
// KSplit templated: 16 if ws fits (8 blocks/CU -> 32 waves/CU), else 8.
template <int KSPLIT>
__global__ __launch_bounds__(256, 8) void gemm_k(
    const float* __restrict__ x, const unsigned int* __restrict__ whl,
    float* __restrict__ part)
{
    constexpr int KLEN = NH / KSPLIT;
    const int lane = threadIdx.x & 63;
    const int wv   = threadIdx.x >> 6;       // 0..3
    const int tg   = blockIdx.x;             // 0..127
    const int ks   = blockIdx.y;             // 0..KSPLIT-1
    const int arow = lane & 15;              // A row (token) / B col (expert)
    const int kg   = lane >> 4;              // k-group: elems kg*8..kg*8+7

    const float* xrow = x + (size_t)(tg * 64 + wv * 16 + arow) * NH
                          + ks * KLEN + kg * 8;
    const unsigned int* wh = whl + ks * (KLEN / 2) + kg * 4;

    f32x4 acc[4];
#pragma unroll
    for (int n = 0; n < 4; ++n) acc[n] = (f32x4){0.f, 0.f, 0.f, 0.f};

    for (int kk = 0; kk < KLEN / 32; ++kk) {          // 10 (KS16) / 20 (KS8)
        const float4 a0 = *reinterpret_cast<const float4*>(xrow + kk * 32);
        const float4 a1 = *reinterpret_cast<const float4*>(xrow + kk * 32 + 4);
        Frag ah, am, al;
        split3_2(a0.x, a0.y, ah.u[0], am.u[0], al.u[0]);
        split3_2(a0.z, a0.w, ah.u[1], am.u[1], al.u[1]);
        split3_2(a1.x, a1.y, ah.u[2], am.u[2], al.u[2]);
        split3_2(a1.z, a1.w, ah.u[3], am.u[3], al.u[3]);
#pragma unroll
        for (int n = 0; n < 4; ++n) {
            const size_t erow = (size_t)(n * 16 + arow) * (NH / 2) + kk * 16;
            Frag bh, bm, bl;
            *reinterpret_cast<int4*>(bh.u) =
                *reinterpret_cast<const int4*>(wh + erow);
            *reinterpret_cast<int4*>(bm.u) =
                *reinterpret_cast<const int4*>(wh + NP + erow);
            *reinterpret_cast<int4*>(bl.u) =
                *reinterpret_cast<const int4*>(wh + 2 * NP + erow);
            acc[n] = __builtin_amdgcn_mfma_f32_16x16x32_bf16(ah.v, bh.v, acc[n], 0, 0, 0);
            acc[n] = __builtin_amdgcn_mfma_f32_16x16x32_bf16(am.v, bh.v, acc[n], 0, 0, 0);
            acc[n] = __builtin_amdgcn_mfma_f32_16x16x32_bf16(ah.v, bm.v, acc[n], 0, 0, 0);
            acc[n] = __builtin_amdgcn_mfma_f32_16x16x32_bf16(am.v, bm.v, acc[n], 0, 0, 0);
            acc[n] = __builtin_amdgcn_mfma_f32_16x16x32_bf16(al.v, bh.v, acc[n], 0, 0, 0);
            acc[n] = __builtin_amdgcn_mfma_f32_16x16x32_bf16(ah.v, bl.v, acc[n], 0, 0, 0);
        }
    }

    // C layout (16x16x32): col(expert)=lane&15, row(token)=(lane>>4)*4+i.
    float* pb = part + (((size_t)ks * NTG + tg) * 64) * 64;
#pragma unroll
    for (int n = 0; n < 4; ++n)
#pragma unroll
        for (int i = 0; i < 4; ++i) {
            const int tokl = wv * 16 + kg * 4 + i;
            const int e    = n * 16 + arow;
            pb[(size_t)tokl * 64 + e] = acc[n][i];
        }
}

// Kernel 2: parallel K-split reduction + bias, IN-PLACE into plane 0.
// Each thread owns one float4 of the [tok][e] plane: read nks planes, sum,
// write back to plane 0. One thread per cell -> no cross-thread hazard.
__global__ __launch_bounds__(256) void reduce_k(
    float4* __restrict__ part4, const float4* __restrict__ bias4, int nks)
{
    const int i = blockIdx.x * 256 + threadIdx.x;    // 0..131071
    float4 acc = bias4[i & 15];                      // e-quad broadcast (NE=64)
    for (int p = 0; p < nks; ++p) {
        const float4 v = part4[(size_t)p * (LOGN / 4) + i];
        acc.x += v.x; acc.y += v.y; acc.z += v.z; acc.w += v.w;
    }
    part4[i] = acc;
}

// Kernel 3: lane-local top-8 + softmax from logits (= plane 0). 1 wave/block,
// 128 blocks; 16 independent float4 loads per lane (L3-warm).
__global__ __launch_bounds__(64) void topk_k(
    const float* __restrict__ logits, float* __restrict__ out)
{
    const int t = blockIdx.x * 64 + (threadIdx.x & 63);

    float acc[NE];
    const float4* lp = reinterpret_cast<const float4*>(logits + (size_t)t * NE);
#pragma unroll
    for (int e4 = 0; e4 < 16; ++e4) {
        const float4 v = lp[e4];
        acc[e4 * 4 + 0] = v.x; acc[e4 * 4 + 1] = v.y;
        acc[e4 * 4 + 2] = v.z; acc[e4 * 4 + 3] = v.w;
    }

    // top-8, strict > keeps lowest index on ties (matches lax.top_k)
    float vals[TOPK]; int idxs[TOPK];
#pragma unroll
    for (int k = 0; k < TOPK; ++k) {
        float m = -INFINITY; int mi = 0;
#pragma unroll
        for (int e = 0; e < NE; ++e) {
            const bool b = acc[e] > m;
            m  = b ? acc[e] : m;
            mi = b ? e  : mi;
        }
        vals[k] = m; idxs[k] = mi;
#pragma unroll
        for (int e = 0; e < NE; ++e)
            acc[e] = (e == mi) ? -INFINITY : acc[e];
    }

    float wts[TOPK];
    float s = 0.f;
#pragma unroll
    for (int k = 0; k < TOPK; ++k) { wts[k] = __expf(vals[k] - vals[0]); s += wts[k]; }
    const float inv = 1.f / s;
#pragma unroll
    for (int k = 0; k < TOPK; ++k) wts[k] *= inv;

    float4 i0, i1, w0, w1;
    i0.x = (float)idxs[0]; i0.y = (float)idxs[1]; i0.z = (float)idxs[2]; i0.w = (float)idxs[3];
    i1.x = (float)idxs[4]; i1.y = (float)idxs[5]; i1.z = (float)idxs[6]; i1.w = (float)idxs[7];
    w0.x = wts[0]; w0.y = wts[1]; w0.z = wts[2]; w0.w = wts[3];
    w1.x = wts[4]; w1.y = wts[5]; w1.z = wts[6]; w1.w = wts[7];

    float* oi = out + (size_t)t * TOPK;
    float* ow = out + (size_t)TOK * TOPK + (size_t)t * TOPK;
    *reinterpret_cast<float4*>(oi)     = i0;
    *reinterpret_cast<float4*>(oi + 4) = i1;
    *reinterpret_cast<float4*>(ow)     = w0;
    *reinterpret_cast<float4*>(ow + 4) = w1;
}

extern "C" void kernel_launch(void* const* d_in, const int* in_sizes, int n_in,
                              void* d_out, int out_size, void* d_ws, size_t ws_size,
                              hipStream_t stream)
{
    const float* x    = (const float*)d_in[0];
    const float* w    = (const float*)d_in[1];
    const float* bias = (const float*)d_in[2];
    float* out = (float*)d_out;

    // ws layout: partials [KS][TOK][NE] f32, then 3 packed bf16 planes.
    const size_t whl_bytes = (size_t)3 * NP * sizeof(unsigned int); // 1.97 MB
    const size_t part16    = (size_t)16 * LOGN * sizeof(float);     // 33.55 MB
    const int KS = (ws_size >= part16 + whl_bytes) ? 16 : 8;

    float*        part = (float*)d_ws;
    unsigned int* whl  = (unsigned int*)((char*)d_ws
                         + (size_t)KS * LOGN * sizeof(float));

    wsplit_k<<<dim3((NE * NH / 4) / 256), 256, 0, stream>>>(w, whl);
    if (KS == 16)
        gemm_k<16><<<dim3(NTG, 16), 256, 0, stream>>>(x, whl, part);
    else
        gemm_k<8><<<dim3(NTG, 8), 256, 0, stream>>>(x, whl, part);
    reduce_k<<<dim3(LOGN / 4 / 256), 256, 0, stream>>>(
        (float4*)part, (const float4*)bias, KS);
    topk_k<<<dim3(NTG), 64, 0, stream>>>(part, out);
}

// Round 9
// 298.988 us; speedup vs baseline: 2.3186x; 1.2006x over previous
//
#include <hip/hip_runtime.h>
#include <hip/hip_bf16.h>
#include <math.h>

#define TOK  8192
#define NE   64
#define NH   5120
#define TOPK 8
#define NTG  (TOK / 64)     // 128 token groups of 64
#define NP   (NE * NH / 2)  // u32 words per packed bf16 plane (163840)
#define LOGN (TOK * NE)     // logits element count (524288)
#define NKB  (NH / 32)      // global k-blocks of 32 (160)

typedef __attribute__((ext_vector_type(8))) short bf16x8;   // 8 bf16 (4 VGPRs)
typedef __attribute__((ext_vector_type(4))) float f32x4;

union Frag { unsigned int u[4]; bf16x8 v; };

// 3-way truncation split: x = hi + mid + lo, each bf16 (8 mantissa bits).
// hi/mid exact truncations, lo rounded half-up. Packs element pair (x0,x1)
// into one u32 per plane via v_perm — IDENTICAL packing for A and B, so any
// within-pair k-permutation cancels in the MFMA dot product.
__device__ __forceinline__ void split3_2(float x0, float x1,
    unsigned int& hi, unsigned int& mid, unsigned int& lo)
{
    unsigned int u0 = __float_as_uint(x0), u1 = __float_as_uint(x1);
    float h0 = __uint_as_float(u0 & 0xffff0000u);    // exact bf16 trunc
    float h1 = __uint_as_float(u1 & 0xffff0000u);
    hi = __builtin_amdgcn_perm(u1, u0, 0x07060302u);
    float r0 = x0 - h0, r1 = x1 - h1;                // exact residual
    unsigned int m0u = __float_as_uint(r0) & 0xffff0000u;
    unsigned int m1u = __float_as_uint(r1) & 0xffff0000u;
    mid = __builtin_amdgcn_perm(m1u, m0u, 0x07060302u);
    float l0 = r0 - __uint_as_float(m0u);            // exact residual
    float l1 = r1 - __uint_as_float(m1u);
    unsigned int v0 = __float_as_uint(l0) + 0x8000u; // round-half-up to bf16
    unsigned int v1 = __float_as_uint(l1) + 0x8000u;
    lo = __builtin_amdgcn_perm(v1, v0, 0x07060302u);
}

// Kernel 0: weights fp32 [64][5120] -> 3 bf16 planes in FRAG-MAJOR tiling:
//   word index = p*NP + kb*1024 + kg*256 + e*4 + j
// (kb = k>>5, kg = (k>>3)&3, j = (k>>1)&3). A B-frag (8 bf16 = 4 u32) for
// (e, kg) is 16B contiguous, and consecutive e are consecutive 16B chunks ->
// gemm_k's B loads are perfectly sequential/coalesced instead of 10KB-stride
// gathers (the R7 L2-request bottleneck).
__global__ __launch_bounds__(256) void wsplit_k(const float* __restrict__ w,
                                                unsigned int* __restrict__ whl)
{
    const int t  = blockIdx.x * 256 + threadIdx.x;  // 40960 threads
    const int k8 = t % (NH / 8);                    // 8-k group within row
    const int e  = t / (NH / 8);
    const int kb = k8 >> 2;
    const int kg = k8 & 3;

    const float4* xp = reinterpret_cast<const float4*>(w + (size_t)e * NH + k8 * 8);
    const float4 a = xp[0], b = xp[1];

    uint4 h, m, l;
    split3_2(a.x, a.y, h.x, m.x, l.x);
    split3_2(a.z, a.w, h.y, m.y, l.y);
    split3_2(b.x, b.y, h.z, m.z, l.z);
    split3_2(b.z, b.w, h.w, m.w, l.w);

    const size_t o = (size_t)kb * 1024 + kg * 256 + e * 4;
    *reinterpret_cast<uint4*>(whl + o)          = h;
    *reinterpret_cast<uint4*>(whl + NP + o)     = m;
    *reinterpret_cast<uint4*>(whl + 2 * NP + o) = l;
}

// Kernel 1: triple-split bf16 MFMA GEMM. Block = 64 tokens x 64 experts x KLEN.
// Wave w owns 16 tokens; A fp32 loaded per-lane from HBM, split in-register;
// B frags loaded per-lane from the frag-major tiled layout (sequential 16B
// chunks, L1/L2-friendly). No LDS, no barriers.
template <int KSPLIT>
__global__ __launch_bounds__(256, 4) void gemm_k(
    const float* __restrict__ x, const unsigned int* __restrict__ whl,
    float* __restrict__ part)
{
    constexpr int KLEN = NH / KSPLIT;
    const int lane = threadIdx.x & 63;
    const int wv   = threadIdx.x >> 6;       // 0..3
    const int tg   = blockIdx.x;             // 0..127
    const int ks   = blockIdx.y;             // 0..KSPLIT-1
    const int arow = lane & 15;              // A row (token) / B col (expert)
    const int kg   = lane >> 4;              // k-group: elems kg*8..kg*8+7

    const float* xrow = x + (size_t)(tg * 64 + wv * 16 + arow) * NH
                          + ks * KLEN + kg * 8;
    // frag-major: word = kblk*1024 + kg*256 + e*4 (+ n*64 for e=n*16+arow)
    const unsigned int* wb0 = whl + (size_t)(ks * (KLEN / 32)) * 1024
                                  + kg * 256 + arow * 4;

    f32x4 acc[4];
#pragma unroll
    for (int n = 0; n < 4; ++n) acc[n] = (f32x4){0.f, 0.f, 0.f, 0.f};

    for (int kk = 0; kk < KLEN / 32; ++kk) {          // 10 (KS16) / 20 (KS8)
        const float4 a0 = *reinterpret_cast<const float4*>(xrow + kk * 32);
        const float4 a1 = *reinterpret_cast<const float4*>(xrow + kk * 32 + 4);
        Frag ah, am, al;
        split3_2(a0.x, a0.y, ah.u[0], am.u[0], al.u[0]);
        split3_2(a0.z, a0.w, ah.u[1], am.u[1], al.u[1]);
        split3_2(a1.x, a1.y, ah.u[2], am.u[2], al.u[2]);
        split3_2(a1.z, a1.w, ah.u[3], am.u[3], al.u[3]);
        const unsigned int* wk = wb0 + (size_t)kk * 1024;
#pragma unroll
        for (int n = 0; n < 4; ++n) {
            Frag bh, bm, bl;
            *reinterpret_cast<int4*>(bh.u) =
                *reinterpret_cast<const int4*>(wk + n * 64);
            *reinterpret_cast<int4*>(bm.u) =
                *reinterpret_cast<const int4*>(wk + NP + n * 64);
            *reinterpret_cast<int4*>(bl.u) =
                *reinterpret_cast<const int4*>(wk + 2 * NP + n * 64);
            acc[n] = __builtin_amdgcn_mfma_f32_16x16x32_bf16(ah.v, bh.v, acc[n], 0, 0, 0);
            acc[n] = __builtin_amdgcn_mfma_f32_16x16x32_bf16(am.v, bh.v, acc[n], 0, 0, 0);
            acc[n] = __builtin_amdgcn_mfma_f32_16x16x32_bf16(ah.v, bm.v, acc[n], 0, 0, 0);
            acc[n] = __builtin_amdgcn_mfma_f32_16x16x32_bf16(am.v, bm.v, acc[n], 0, 0, 0);
            acc[n] = __builtin_amdgcn_mfma_f32_16x16x32_bf16(al.v, bh.v, acc[n], 0, 0, 0);
            acc[n] = __builtin_amdgcn_mfma_f32_16x16x32_bf16(ah.v, bl.v, acc[n], 0, 0, 0);
        }
    }

    // C layout (16x16x32): col(expert)=lane&15, row(token)=(lane>>4)*4+i.
    float* pb = part + (((size_t)ks * NTG + tg) * 64) * 64;
#pragma unroll
    for (int n = 0; n < 4; ++n)
#pragma unroll
        for (int i = 0; i < 4; ++i) {
            const int tokl = wv * 16 + kg * 4 + i;
            const int e    = n * 16 + arow;
            pb[(size_t)tokl * 64 + e] = acc[n][i];
        }
}

// Kernel 2: parallel K-split reduction + bias, IN-PLACE into plane 0.
__global__ __launch_bounds__(256) void reduce_k(
    float4* __restrict__ part4, const float4* __restrict__ bias4, int nks)
{
    const int i = blockIdx.x * 256 + threadIdx.x;    // 0..131071
    float4 acc = bias4[i & 15];                      // e-quad broadcast (NE=64)
    for (int p = 0; p < nks; ++p) {
        const float4 v = part4[(size_t)p * (LOGN / 4) + i];
        acc.x += v.x; acc.y += v.y; acc.z += v.z; acc.w += v.w;
    }
    part4[i] = acc;
}

// Kernel 3: lane-local top-8 + softmax from logits (= plane 0).
__global__ __launch_bounds__(64) void topk_k(
    const float* __restrict__ logits, float* __restrict__ out)
{
    const int t = blockIdx.x * 64 + (threadIdx.x & 63);

    float acc[NE];
    const float4* lp = reinterpret_cast<const float4*>(logits + (size_t)t * NE);
#pragma unroll
    for (int e4 = 0; e4 < 16; ++e4) {
        const float4 v = lp[e4];
        acc[e4 * 4 + 0] = v.x; acc[e4 * 4 + 1] = v.y;
        acc[e4 * 4 + 2] = v.z; acc[e4 * 4 + 3] = v.w;
    }

    // top-8, strict > keeps lowest index on ties (matches lax.top_k)
    float vals[TOPK]; int idxs[TOPK];
#pragma unroll
    for (int k = 0; k < TOPK; ++k) {
        float m = -INFINITY; int mi = 0;
#pragma unroll
        for (int e = 0; e < NE; ++e) {
            const bool b = acc[e] > m;
            m  = b ? acc[e] : m;
            mi = b ? e  : mi;
        }
        vals[k] = m; idxs[k] = mi;
#pragma unroll
        for (int e = 0; e < NE; ++e)
            acc[e] = (e == mi) ? -INFINITY : acc[e];
    }

    float wts[TOPK];
    float s = 0.f;
#pragma unroll
    for (int k = 0; k < TOPK; ++k) { wts[k] = __expf(vals[k] - vals[0]); s += wts[k]; }
    const float inv = 1.f / s;
#pragma unroll
    for (int k = 0; k < TOPK; ++k) wts[k] *= inv;

    float4 i0, i1, w0, w1;
    i0.x = (float)idxs[0]; i0.y = (float)idxs[1]; i0.z = (float)idxs[2]; i0.w = (float)idxs[3];
    i1.x = (float)idxs[4]; i1.y = (float)idxs[5]; i1.z = (float)idxs[6]; i1.w = (float)idxs[7];
    w0.x = wts[0]; w0.y = wts[1]; w0.z = wts[2]; w0.w = wts[3];
    w1.x = wts[4]; w1.y = wts[5]; w1.z = wts[6]; w1.w = wts[7];

    float* oi = out + (size_t)t * TOPK;
    float* ow = out + (size_t)TOK * TOPK + (size_t)t * TOPK;
    *reinterpret_cast<float4*>(oi)     = i0;
    *reinterpret_cast<float4*>(oi + 4) = i1;
    *reinterpret_cast<float4*>(ow)     = w0;
    *reinterpret_cast<float4*>(ow + 4) = w1;
}

extern "C" void kernel_launch(void* const* d_in, const int* in_sizes, int n_in,
                              void* d_out, int out_size, void* d_ws, size_t ws_size,
                              hipStream_t stream)
{
    const float* x    = (const float*)d_in[0];
    const float* w    = (const float*)d_in[1];
    const float* bias = (const float*)d_in[2];
    float* out = (float*)d_out;

    // ws layout: partials [KS][TOK][NE] f32, then 3 tiled bf16 planes.
    const size_t whl_bytes = (size_t)3 * NP * sizeof(unsigned int); // 1.97 MB
    const size_t part16    = (size_t)16 * LOGN * sizeof(float);     // 33.55 MB
    const int KS = (ws_size >= part16 + whl_bytes) ? 16 : 8;

    float*        part = (float*)d_ws;
    unsigned int* whl  = (unsigned int*)((char*)d_ws
                         + (size_t)KS * LOGN * sizeof(float));

    wsplit_k<<<dim3((NE * NH / 8) / 256), 256, 0, stream>>>(w, whl);
    if (KS == 16)
        gemm_k<16><<<dim3(NTG, 16), 256, 0, stream>>>(x, whl, part);
    else
        gemm_k<8><<<dim3(NTG, 8), 256, 0, stream>>>(x, whl, part);
    reduce_k<<<dim3(LOGN / 4 / 256), 256, 0, stream>>>(
        (float4*)part, (const float4*)bias, KS);
    topk_k<<<dim3(NTG), 64, 0, stream>>>(part, out);
}

// Round 11
// 277.288 us; speedup vs baseline: 2.5000x; 1.0783x over previous
//
#include <hip/hip_runtime.h>
#include <hip/hip_bf16.h>
#include <math.h>

#define TOK  8192
#define NE   64
#define NH   5120
#define TOPK 8
#define NP   (NE * NH / 2)  // u32 words per packed bf16 plane (163840)
#define LOGN (TOK * NE)     // logits element count (524288)

typedef __attribute__((ext_vector_type(8))) short bf16x8;   // 8 bf16 (4 VGPRs)
typedef __attribute__((ext_vector_type(4))) float f32x4;

union Frag { unsigned int u[4]; bf16x8 v; };

// 3-way truncation split: x = hi + mid + lo, each bf16 (8 mantissa bits).
// hi/mid exact truncations, lo rounded half-up. Packs element pair (x0,x1)
// into one u32 per plane via v_perm — IDENTICAL packing for A and B, so any
// within-pair k-permutation cancels in the MFMA dot product.
__device__ __forceinline__ void split3_2(float x0, float x1,
    unsigned int& hi, unsigned int& mid, unsigned int& lo)
{
    unsigned int u0 = __float_as_uint(x0), u1 = __float_as_uint(x1);
    float h0 = __uint_as_float(u0 & 0xffff0000u);    // exact bf16 trunc
    float h1 = __uint_as_float(u1 & 0xffff0000u);
    hi = __builtin_amdgcn_perm(u1, u0, 0x07060302u);
    float r0 = x0 - h0, r1 = x1 - h1;                // exact residual
    unsigned int m0u = __float_as_uint(r0) & 0xffff0000u;
    unsigned int m1u = __float_as_uint(r1) & 0xffff0000u;
    mid = __builtin_amdgcn_perm(m1u, m0u, 0x07060302u);
    float l0 = r0 - __uint_as_float(m0u);            // exact residual
    float l1 = r1 - __uint_as_float(m1u);
    unsigned int v0 = __float_as_uint(l0) + 0x8000u; // round-half-up to bf16
    unsigned int v1 = __float_as_uint(l1) + 0x8000u;
    lo = __builtin_amdgcn_perm(v1, v0, 0x07060302u);
}

// Kernel 0: weights fp32 [64][5120] -> 3 bf16 planes in FRAG-MAJOR tiling:
//   word index = p*NP + kb*1024 + kg*256 + e*4 + j
// (kb = k>>5, kg = (k>>3)&3, j = (k>>1)&3). A B-frag (8 bf16 = 4 u32) for
// (e, kg) is 16B contiguous; consecutive e are consecutive 16B chunks.
__global__ __launch_bounds__(256) void wsplit_k(const float* __restrict__ w,
                                                unsigned int* __restrict__ whl)
{
    const int t  = blockIdx.x * 256 + threadIdx.x;  // 40960 threads
    const int k8 = t % (NH / 8);                    // 8-k group within row
    const int e  = t / (NH / 8);
    const int kb = k8 >> 2;
    const int kg = k8 & 3;

    const float4* xp = reinterpret_cast<const float4*>(w + (size_t)e * NH + k8 * 8);
    const float4 a = xp[0], b = xp[1];

    uint4 h, m, l;
    split3_2(a.x, a.y, h.x, m.x, l.x);
    split3_2(a.z, a.w, h.y, m.y, l.y);
    split3_2(b.x, b.y, h.z, m.z, l.z);
    split3_2(b.z, b.w, h.w, m.w, l.w);

    const size_t o = (size_t)kb * 1024 + kg * 256 + e * 4;
    *reinterpret_cast<uint4*>(whl + o)          = h;
    *reinterpret_cast<uint4*>(whl + NP + o)     = m;
    *reinterpret_cast<uint4*>(whl + 2 * NP + o) = l;
}

// Kernel 1: triple-split bf16 MFMA GEMM, HIGH-INTENSITY wave tiles.
// Block = 256 threads = 4 waves; each wave owns 64 tokens x 64 experts x KLEN.
// Per kk-step: 12 B-frag loads (reused across 4 m-groups) + 8 A-loads ->
// 96 MFMAs (4.8 MFMA/load vs R9's 1.7). Grid 512 blocks = 2/CU; only 2
// waves/SIMD resident so the compiler has ~250 VGPRs for pipelining.
template <int KSPLIT>
__global__ __launch_bounds__(256) void gemm_k(
    const float* __restrict__ x, const unsigned int* __restrict__ whl,
    float* __restrict__ part)
{
    constexpr int KLEN = NH / KSPLIT;        // 320 (KS=16)
    const int lane = threadIdx.x & 63;
    const int wv   = threadIdx.x >> 6;       // 0..3
    const int tg   = blockIdx.x;             // 0..31
    const int ks   = blockIdx.y;             // 0..KSPLIT-1
    const int arow = lane & 15;              // A row within 16 / B col (expert)
    const int kg   = lane >> 4;              // k-group: elems kg*8..kg*8+7

    const int trow0 = tg * 256 + wv * 64;    // wave's first token
    const float* xbase = x + (size_t)trow0 * NH + ks * KLEN + kg * 8;
    // frag-major: word = kblk*1024 + kg*256 + e*4 (+ n*64 for e=n*16+arow)
    const unsigned int* wb0 = whl + (size_t)(ks * (KLEN / 32)) * 1024
                                  + kg * 256 + arow * 4;

    f32x4 acc[4][4];
#pragma unroll
    for (int m = 0; m < 4; ++m)
#pragma unroll
        for (int n = 0; n < 4; ++n) acc[m][n] = (f32x4){0.f, 0.f, 0.f, 0.f};

#pragma unroll 2
    for (int kk = 0; kk < KLEN / 32; ++kk) {          // 10 steps (KS=16)
        const unsigned int* wk = wb0 + (size_t)kk * 1024;
        Frag bh[4], bm[4], bl[4];
#pragma unroll
        for (int n = 0; n < 4; ++n) {
            *reinterpret_cast<int4*>(bh[n].u) =
                *reinterpret_cast<const int4*>(wk + n * 64);
            *reinterpret_cast<int4*>(bm[n].u) =
                *reinterpret_cast<const int4*>(wk + NP + n * 64);
            *reinterpret_cast<int4*>(bl[n].u) =
                *reinterpret_cast<const int4*>(wk + 2 * NP + n * 64);
        }
#pragma unroll
        for (int m = 0; m < 4; ++m) {
            const float* xr = xbase + (size_t)(m * 16 + arow) * NH + kk * 32;
            const float4 a0 = *reinterpret_cast<const float4*>(xr);
            const float4 a1 = *reinterpret_cast<const float4*>(xr + 4);
            Frag ah, am_, al;
            split3_2(a0.x, a0.y, ah.u[0], am_.u[0], al.u[0]);
            split3_2(a0.z, a0.w, ah.u[1], am_.u[1], al.u[1]);
            split3_2(a1.x, a1.y, ah.u[2], am_.u[2], al.u[2]);
            split3_2(a1.z, a1.w, ah.u[3], am_.u[3], al.u[3]);
#pragma unroll
            for (int n = 0; n < 4; ++n) {
                acc[m][n] = __builtin_amdgcn_mfma_f32_16x16x32_bf16(ah.v,  bh[n].v, acc[m][n], 0, 0, 0);
                acc[m][n] = __builtin_amdgcn_mfma_f32_16x16x32_bf16(am_.v, bh[n].v, acc[m][n], 0, 0, 0);
                acc[m][n] = __builtin_amdgcn_mfma_f32_16x16x32_bf16(ah.v,  bm[n].v, acc[m][n], 0, 0, 0);
                acc[m][n] = __builtin_amdgcn_mfma_f32_16x16x32_bf16(am_.v, bm[n].v, acc[m][n], 0, 0, 0);
                acc[m][n] = __builtin_amdgcn_mfma_f32_16x16x32_bf16(al.v,  bh[n].v, acc[m][n], 0, 0, 0);
                acc[m][n] = __builtin_amdgcn_mfma_f32_16x16x32_bf16(ah.v,  bl[n].v, acc[m][n], 0, 0, 0);
            }
        }
    }

    // C layout (16x16x32): col(expert)=lane&15, row(token)=(lane>>4)*4+i.
    // part[ks][tok][e]; each 16-lane group stores one 64B-contiguous run.
    float* pb = part + ((size_t)ks * TOK + trow0) * 64;
#pragma unroll
    for (int m = 0; m < 4; ++m)
#pragma unroll
        for (int n = 0; n < 4; ++n)
#pragma unroll
            for (int i = 0; i < 4; ++i) {
                const int tokl = m * 16 + kg * 4 + i;
                const int e    = n * 16 + arow;
                pb[(size_t)tokl * 64 + e] = acc[m][n][i];
            }
}

// Kernel 2: FUSED reduce + bias + top-8 + softmax. Block = 256 threads owns
// 16 tokens. Phase 1: thread t owns cell (tok=t>>4, equad=t&15); reads nks
// planes fully coalesced (plane float4-index = blk*256 + t), sums with bias,
// stages into padded LDS. Phase 2: lanes 0-15 do per-token top-8 from LDS
// (row stride 65 -> bank-conflict-free scalar reads).
__global__ __launch_bounds__(256) void redtopk_k(
    const float4* __restrict__ part4, const float4* __restrict__ bias4,
    float* __restrict__ out, int nks)
{
    __shared__ float lds[16][65];
    const int t   = threadIdx.x;
    const int blk = blockIdx.x;                       // 0..511

    float4 acc4 = bias4[t & 15];
    const size_t base = (size_t)blk * 256 + t;
    for (int p = 0; p < nks; ++p) {
        const float4 v = part4[(size_t)p * (LOGN / 4) + base];
        acc4.x += v.x; acc4.y += v.y; acc4.z += v.z; acc4.w += v.w;
    }
    const int tok = t >> 4, eq = t & 15;
    lds[tok][eq * 4 + 0] = acc4.x;
    lds[tok][eq * 4 + 1] = acc4.y;
    lds[tok][eq * 4 + 2] = acc4.z;
    lds[tok][eq * 4 + 3] = acc4.w;
    __syncthreads();

    if (t < 16) {
        float acc[NE];
#pragma unroll
        for (int e = 0; e < NE; ++e) acc[e] = lds[t][e];

        // top-8, strict > keeps lowest index on ties (matches lax.top_k)
        float vals[TOPK]; int idxs[TOPK];
#pragma unroll
        for (int k = 0; k < TOPK; ++k) {
            float m = -INFINITY; int mi = 0;
#pragma unroll
            for (int e = 0; e < NE; ++e) {
                const bool b = acc[e] > m;
                m  = b ? acc[e] : m;
                mi = b ? e  : mi;
            }
            vals[k] = m; idxs[k] = mi;
#pragma unroll
            for (int e = 0; e < NE; ++e)
                acc[e] = (e == mi) ? -INFINITY : acc[e];
        }

        float wts[TOPK];
        float s = 0.f;
#pragma unroll
        for (int k = 0; k < TOPK; ++k) { wts[k] = __expf(vals[k] - vals[0]); s += wts[k]; }
        const float inv = 1.f / s;
#pragma unroll
        for (int k = 0; k < TOPK; ++k) wts[k] *= inv;

        float4 i0, i1, w0, w1;
        i0.x = (float)idxs[0]; i0.y = (float)idxs[1]; i0.z = (float)idxs[2]; i0.w = (float)idxs[3];
        i1.x = (float)idxs[4]; i1.y = (float)idxs[5]; i1.z = (float)idxs[6]; i1.w = (float)idxs[7];
        w0.x = wts[0]; w0.y = wts[1]; w0.z = wts[2]; w0.w = wts[3];
        w1.x = wts[4]; w1.y = wts[5]; w1.z = wts[6]; w1.w = wts[7];

        const int token = blk * 16 + t;
        float* oi = out + (size_t)token * TOPK;
        float* ow = out + (size_t)TOK * TOPK + (size_t)token * TOPK;
        *reinterpret_cast<float4*>(oi)     = i0;
        *reinterpret_cast<float4*>(oi + 4) = i1;
        *reinterpret_cast<float4*>(ow)     = w0;
        *reinterpret_cast<float4*>(ow + 4) = w1;
    }
}

extern "C" void kernel_launch(void* const* d_in, const int* in_sizes, int n_in,
                              void* d_out, int out_size, void* d_ws, size_t ws_size,
                              hipStream_t stream)
{
    const float* x    = (const float*)d_in[0];
    const float* w    = (const float*)d_in[1];
    const float* bias = (const float*)d_in[2];
    float* out = (float*)d_out;

    // ws layout: partials [KS][TOK][NE] f32, then 3 tiled bf16 planes.
    const size_t whl_bytes = (size_t)3 * NP * sizeof(unsigned int); // 1.97 MB
    const size_t part16    = (size_t)16 * LOGN * sizeof(float);     // 33.55 MB
    const int KS = (ws_size >= part16 + whl_bytes) ? 16 : 8;

    float*        part = (float*)d_ws;
    unsigned int* whl  = (unsigned int*)((char*)d_ws
                         + (size_t)KS * LOGN * sizeof(float));

    wsplit_k<<<dim3((NE * NH / 8) / 256), 256, 0, stream>>>(w, whl);
    if (KS == 16)
        gemm_k<16><<<dim3(TOK / 256, 16), 256, 0, stream>>>(x, whl, part);
    else
        gemm_k<8><<<dim3(TOK / 256, 8), 256, 0, stream>>>(x, whl, part);
    redtopk_k<<<dim3(TOK / 16), 256, 0, stream>>>(
        (const float4*)part, (const float4*)bias, out, KS);
}